// Round 12
// baseline (94.266 us; speedup 1.0000x reference)
//
#include <hip/hip_runtime.h>
#include <hip/hip_bf16.h>

// B=8, Lq=2048, Lk=2048, D=256. out = softmax(mask? sq_i+sk_j : -1e9) @ V.
// sq cancels in softmax => out[i] = (mask[i]·(e*V)) / (mask[i]·e), e=exp(K·w).
// SINGLE fused cooperative kernel, grid 256 x 512 thr:
//   Phase 1: block (b,itile) produces its OWN evB pair (k-slices 2*itile,
//     2*itile+1) + eb rows, then sets flags[b][itile] (release, agent scope).
//   Phase 2: round-11 gemm (BM=64 x BN=256 x BK=64, 8 waves 2m x 4n), k-loop
//     ROTATED to start at the block's own pair (k-order-independent sum,
//     fixed per block => deterministic). Foreign pairs gated by a 1-atomic-
//     per-wave spin (stagger => ~never taken; cooperative launch => resident
//     => deadlock-free). A-staging = round-10 proven 0-conflict pattern
//     (4 thr/row, threads 0..255). B/e reg-prefetched 1 step ahead; A 2 steps;
//     per-step sync = lgkmcnt(0)+s_barrier only (vmcnt never drained).
//     Denominator folded into MFMA via e-column B-frag (wn==0 waves).
// Workspace: evB 8 MB + eb 32 KB + flags 1 KB (memset to 0 each call).

#define NB 8
#define LQ 2048
#define LK 2048
#define DD 256

typedef __attribute__((ext_vector_type(8))) short short8v;
typedef __attribute__((ext_vector_type(8))) unsigned short ushort8v;
typedef __attribute__((ext_vector_type(4))) float f32x4;

__device__ inline unsigned short f2bf(float x) {
  union { __hip_bfloat16 h; unsigned short u; } cv;
  cv.h = __float2bfloat16(x);
  return cv.u;
}

__device__ inline uint2 pack_mask4(const int4 a) {
  uint2 p;
  p.x = (a.x ? 0x3F80u : 0u) | (a.y ? 0x3F800000u : 0u);
  p.y = (a.z ? 0x3F80u : 0u) | (a.w ? 0x3F800000u : 0u);
  return p;
}

__global__ __launch_bounds__(512, 1) void bah_fused(
    const float* __restrict__ key, const float* __restrict__ value,
    const float* __restrict__ w, const int* __restrict__ mask,
    unsigned short* __restrict__ evB, unsigned short* __restrict__ eb,
    unsigned int* __restrict__ flags, float* __restrict__ out)
{
  __shared__ unsigned short A_s[3][64 * 64];     // 24.6 KB gemm A ring
  __shared__ unsigned short pre_s[2][32][260];   // 33.3 KB phase-1 transpose
  __shared__ float e_s[2][32];
  __shared__ float denom_s[64];

  const int t = threadIdx.x;
  const int lane = t & 63;
  const int blk = blockIdx.x;
  const int b = blk & 7;                    // batch -> XCD (evB L2-resident)
  const int itile = blk >> 3;               // 0..31
  const int i0 = itile * 64;

  // ---- A staging geometry (threads 0..255; round-10 0-conflict pattern) ----
  const int sr = (t & 255) >> 2;            // 0..63
  const int q = t & 3;
  const int* amask = mask + ((size_t)b * LQ + i0 + sr) * LK + q * 4;
  int awr[4];
#pragma unroll
  for (int j = 0; j < 4; ++j)               // chunk c2=(q>>1)+2j, half q&1
    awr[j] = sr * 64 + ((((q >> 1) + 2 * j + sr) & 7) * 8) + (q & 1) * 4;

  // ---- issue first two A mask tiles NOW (independent of phase 1) ----
  int4 aP[4], aC[4];
  if (t < 256) {
#pragma unroll
    for (int j = 0; j < 4; ++j)
      aP[j] = *reinterpret_cast<const int4*>(amask + itile * 64 + j * 16);
    const int s1 = (itile + 1) & 31;
#pragma unroll
    for (int j = 0; j < 4; ++j)
      aC[j] = *reinterpret_cast<const int4*>(amask + s1 * 64 + j * 16);
  }

  // ================= Phase 1: produce own evB/eb pair =================
  {
    const int hh = t >> 8;                  // 0/1: which slice of the pair
    const int tq = t & 255;
    const int wid4 = tq >> 6;               // 0..3
    const int ks = 2 * itile + hh;
    const int j0 = ks * 32;
    const float4 wv4 = reinterpret_cast<const float4*>(w)[lane];
#pragma unroll
    for (int r8 = 0; r8 < 8; ++r8) {
      const int r = wid4 * 8 + r8;
      const size_t row = (size_t)b * LK + j0 + r;
      const float4 kv = reinterpret_cast<const float4*>(key + row * DD)[lane];
      float s = kv.x * wv4.x + kv.y * wv4.y + kv.z * wv4.z + kv.w * wv4.w;
#pragma unroll
      for (int off = 32; off; off >>= 1) s += __shfl_xor(s, off);
      const float e = __expf(s);            // |K·w| small: no max-shift needed
      if (lane == 0) { e_s[hh][r] = e; eb[row] = f2bf(e); }
    }
    __syncthreads();
#pragma unroll
    for (int g = 0; g < 8; ++g) {
      const int jr = g * 4 + wid4;
      const size_t row = (size_t)b * LK + j0 + jr;
      const float4 vv = reinterpret_cast<const float4*>(value + row * DD)[lane];
      const float e = e_s[hh][jr];
      ushort4 u;
      u.x = f2bf(e * vv.x);
      u.y = f2bf(e * vv.y);
      u.z = f2bf(e * vv.z);
      u.w = f2bf(e * vv.w);
      *reinterpret_cast<ushort4*>(&pre_s[hh][jr][lane * 4]) = u;
    }
    __syncthreads();
    const int lr_ = lane & 15;
    const int lj_ = lane >> 4;
#pragma unroll
    for (int n4 = 0; n4 < 4; ++n4) {
      const int n = wid4 * 4 + n4;
      ushort8v va;
#pragma unroll
      for (int i = 0; i < 8; ++i) va[i] = pre_s[hh][lj_ * 8 + i][n * 16 + lr_];
      *reinterpret_cast<ushort8v*>(
          evB + (size_t)((b * 64 + ks) * 16 + n) * 512 + (size_t)lane * 8) = va;
    }
    __syncthreads();   // all waves drain vmcnt at barrier -> stores complete
    if (t == 0)
      __hip_atomic_store(&flags[b * 32 + itile], 1u, __ATOMIC_RELEASE,
                         __HIP_MEMORY_SCOPE_AGENT);
  }

  // ================= Phase 2: gemm (rotated k-order) =================
  const int wid = t >> 6;
  const int wm = wid >> 2;                  // 0..1: 32-row half
  const int wn = wid & 3;                   // 0..3: 64-d quarter
  const int lr = lane & 15;
  const int lj = lane >> 4;

  const unsigned short* bB[4];
#pragma unroll
  for (int nn = 0; nn < 4; ++nn)
    bB[nn] = evB + ((size_t)(b * 64) * 16 + wn * 4 + nn) * 512 + lane * 8;
  const unsigned short* ebb = eb + b * LK + lj * 8;

  int afo[2][2];
#pragma unroll
  for (int m = 0; m < 2; ++m) {
    const int row = wm * 32 + m * 16 + lr;
#pragma unroll
    for (int h = 0; h < 2; ++h)
      afo[m][h] = row * 64 + (((h * 4 + lj + row) & 7) * 8);
  }

  f32x4 acc[2][4] = {};
  f32x4 accd[2] = {};
  const short8v z8 = {};
  short8v bfr[2][2][4];
  short8v efr[2][2] = {{z8, z8}, {z8, z8}};

  // ---- prologue: A(0) ring0 from aP regs; B/e pair itile (own, just made) ----
  if (t < 256) {
#pragma unroll
    for (int j = 0; j < 4; ++j)
      *reinterpret_cast<uint2*>(&A_s[0][awr[j]]) = pack_mask4(aP[j]);
  }
#pragma unroll
  for (int h = 0; h < 2; ++h) {
#pragma unroll
    for (int nn = 0; nn < 4; ++nn)
      bfr[0][h][nn] = *reinterpret_cast<const short8v*>(
          bB[nn] + (size_t)(2 * itile + h) * 8192);
    if (wn == 0 && lr == 0)
      efr[0][h] = *reinterpret_cast<const short8v*>(ebb + (2 * itile + h) * 32);
  }
  __syncthreads();

#pragma unroll 2
  for (int tt = 0; tt < 32; ++tt) {
    const int cur = tt & 1;
    const int nxt = cur ^ 1;
    const int bufC = tt % 3;
    const int bufW = (tt + 1) % 3;
    const int sW = (itile + tt + 2) & 31;   // A pair, 2 steps ahead
    const int sB = (itile + tt + 1) & 31;   // B/e pair, 1 step ahead

    // ---- issue A(t+2) (no dependency) ----
    int4 aN[4];
    if (t < 256) {
#pragma unroll
      for (int j = 0; j < 4; ++j)
        aN[j] = *reinterpret_cast<const int4*>(amask + sW * 64 + j * 16);
    }
    // ---- gate foreign B/e pair (1 atomic per wave; ~never spins) ----
    if (sB != itile) {
      unsigned int f;
      do {
        f = 1u;
        if (lane == 0)
          f = __hip_atomic_load(&flags[b * 32 + sB], __ATOMIC_RELAXED,
                                __HIP_MEMORY_SCOPE_AGENT);
        f = (unsigned int)__shfl((int)f, 0);
        if (f == 0u) __builtin_amdgcn_s_sleep(2);
      } while (f == 0u);
    }
    // ---- issue B(t+1)/e(t+1) (cross barrier via counted vmcnt) ----
#pragma unroll
    for (int h = 0; h < 2; ++h) {
#pragma unroll
      for (int nn = 0; nn < 4; ++nn)
        bfr[nxt][h][nn] = *reinterpret_cast<const short8v*>(
            bB[nn] + (size_t)(2 * sB + h) * 8192);
      short8v ev = z8;
      if (wn == 0 && lr == 0)
        ev = *reinterpret_cast<const short8v*>(ebb + (2 * sB + h) * 32);
      efr[nxt][h] = ev;
    }
    __builtin_amdgcn_sched_barrier(0);

    // ---- write A(t+1) from regs; certify with lgkm + barrier only ----
    if (t < 256) {
#pragma unroll
      for (int j = 0; j < 4; ++j)
        *reinterpret_cast<uint2*>(&A_s[bufW][awr[j]]) = pack_mask4(aC[j]);
    }
    asm volatile("s_waitcnt lgkmcnt(0)" ::: "memory");
    __builtin_amdgcn_sched_barrier(0);
    __builtin_amdgcn_s_barrier();
    __builtin_amdgcn_sched_barrier(0);

    // ---- compute pair (itile+tt)&31 from LDS-A + reg-B ----
#pragma unroll
    for (int h = 0; h < 2; ++h) {
      short8v af[2];
#pragma unroll
      for (int m = 0; m < 2; ++m)
        af[m] = *reinterpret_cast<const short8v*>(&A_s[bufC][afo[m][h]]);
      __builtin_amdgcn_s_setprio(1);
      if (wn == 0) {
#pragma unroll
        for (int m = 0; m < 2; ++m)
          accd[m] = __builtin_amdgcn_mfma_f32_16x16x32_bf16(
              af[m], efr[cur][h], accd[m], 0, 0, 0);
      }
#pragma unroll
      for (int m = 0; m < 2; ++m)
#pragma unroll
        for (int nn = 0; nn < 4; ++nn)
          acc[m][nn] = __builtin_amdgcn_mfma_f32_16x16x32_bf16(
              af[m], bfr[cur][h][nn], acc[m][nn], 0, 0, 0);
      __builtin_amdgcn_s_setprio(0);
    }
#pragma unroll
    for (int j = 0; j < 4; ++j) aC[j] = aN[j];
  }

  // ---- denominator broadcast (C col 0 lives in lanes with lr==0) ----
  if (wn == 0 && lr == 0) {
#pragma unroll
    for (int m = 0; m < 2; ++m)
#pragma unroll
      for (int qq = 0; qq < 4; ++qq)
        denom_s[wm * 32 + m * 16 + lj * 4 + qq] = accd[m][qq];
  }
  __syncthreads();

  // ---- epilogue: divide and store (C layout: col=lane&15, row=lj*4+q) ----
#pragma unroll
  for (int m = 0; m < 2; ++m) {
    const int row0 = wm * 32 + m * 16 + lj * 4;
    float inv[4];
#pragma unroll
    for (int qq = 0; qq < 4; ++qq) {
      const float dn = denom_s[row0 + qq];
      inv[qq] = (dn != 0.f) ? 1.f / dn : 0.f;   // all-masked row: avoid NaN
    }
#pragma unroll
    for (int nn = 0; nn < 4; ++nn) {
      const int col = wn * 64 + nn * 16 + lr;
#pragma unroll
      for (int qq = 0; qq < 4; ++qq)
        out[((size_t)b * LQ + (i0 + row0 + qq)) * DD + col] = acc[m][nn][qq] * inv[qq];
    }
  }
}

extern "C" void kernel_launch(void* const* d_in, const int* in_sizes, int n_in,
                              void* d_out, int out_size, void* d_ws, size_t ws_size,
                              hipStream_t stream) {
  // inputs: 0=query (unused: softmax shift-invariance), 1=key, 2=value, 3=mask, 4=w_align
  const float* key   = (const float*)d_in[1];
  const float* value = (const float*)d_in[2];
  const int*   mask  = (const int*)d_in[3];
  const float* w     = (const float*)d_in[4];
  float* out = (float*)d_out;

  unsigned short* evB = (unsigned short*)d_ws;                              // 8 MB
  unsigned short* eb  = (unsigned short*)((char*)d_ws + (size_t)NB * DD * LK * 2);
  unsigned int* flags = (unsigned int*)((char*)d_ws + (size_t)NB * DD * LK * 2
                                        + (size_t)NB * LK * 2);             // 1 KB

  hipMemsetAsync(flags, 0, NB * 32 * sizeof(unsigned int), stream);
  void* args[] = {(void*)&key, (void*)&value, (void*)&w, (void*)&mask,
                  (void*)&evB, (void*)&eb, (void*)&flags, (void*)&out};
  hipLaunchCooperativeKernel((void*)bah_fused, dim3(256), dim3(512),
                             args, 0, stream);
}

// Round 13
// 51.418 us; speedup vs baseline: 1.8333x; 1.8333x over previous
//
#include <hip/hip_runtime.h>
#include <hip/hip_bf16.h>

// B=8, Lq=2048, Lk=2048, D=256. out = softmax(mask? sq_i+sk_j : -1e9) @ V.
// sq cancels in softmax => out[i] = (mask[i]·(e*V)) / (mask[i]·e), e=exp(K·w).
// Kernel 1: eb (bf16) + evB (pre-fragmented MFMA B-operand; coalesced loads).
// Kernel 2: mask-streaming GEMM, BM=64 x BN=256 x BK=64, 512 thr (8 waves,
//   2m x 4n), grid 256 = 1 block/CU, mask read EXACTLY once. A staging:
//   8 thr/row, 32 B contiguous per thread (2xint4 -> uint4 pack), LDS slot =
//   chunk ^ (row&7) with uint4 writes — round-9-verified 0-conflict on both
//   write and b128 frag-read sides. A: 3-deep LDS ring, 2-step reg prefetch.
//   B/e: reg prefetch 1 step ahead from L2-resident evB. Sync: lgkmcnt(0)+
//   s_barrier only — vmcnt never drained. Denominator folded into MFMA
//   (e-column B-frag, wn==0 waves).
// Workspace: evB 8 MB + eb 32 KB.

#define NB 8
#define LQ 2048
#define LK 2048
#define DD 256

typedef __attribute__((ext_vector_type(8))) short short8v;
typedef __attribute__((ext_vector_type(8))) unsigned short ushort8v;
typedef __attribute__((ext_vector_type(4))) float f32x4;

__device__ inline unsigned short f2bf(float x) {
  union { __hip_bfloat16 h; unsigned short u; } cv;
  cv.h = __float2bfloat16(x);
  return cv.u;
}

__device__ inline uint4 pack_mask8(const int4 a, const int4 b) {
  uint4 p;
  p.x = (a.x ? 0x3F80u : 0u) | (a.y ? 0x3F800000u : 0u);
  p.y = (a.z ? 0x3F80u : 0u) | (a.w ? 0x3F800000u : 0u);
  p.z = (b.x ? 0x3F80u : 0u) | (b.y ? 0x3F800000u : 0u);
  p.w = (b.z ? 0x3F80u : 0u) | (b.w ? 0x3F800000u : 0u);
  return p;
}

// ---------------- Kernel 1: eb = bf16(exp(K·w)); evB = pre-fragmented e*V -----
// grid 8*64=512 (b = blk&7 -> XCD), 256 thr. Block owns batch b, 32 j-rows (ks).
__global__ __launch_bounds__(256) void bah_precompute(
    const float* __restrict__ key, const float* __restrict__ value,
    const float* __restrict__ w, unsigned short* __restrict__ evB,
    unsigned short* __restrict__ eb)
{
  __shared__ float e_s[32];
  __shared__ unsigned short t_s[32][260];   // padded: conflict-free transpose

  const int t = threadIdx.x;
  const int lane = t & 63;
  const int wid = t >> 6;                   // 0..3
  const int blk = blockIdx.x;
  const int b = blk & 7;
  const int ks = blk >> 3;                  // 0..63 (32-k slice)
  const int j0 = ks * 32;

  const float4 wv4 = reinterpret_cast<const float4*>(w)[lane];

#pragma unroll
  for (int r8 = 0; r8 < 8; ++r8) {
    const int r = wid * 8 + r8;
    const size_t row = (size_t)b * LK + j0 + r;
    const float4 kv = reinterpret_cast<const float4*>(key + row * DD)[lane];
    float s = kv.x * wv4.x + kv.y * wv4.y + kv.z * wv4.z + kv.w * wv4.w;
#pragma unroll
    for (int off = 32; off; off >>= 1) s += __shfl_xor(s, off);
    const float e = __expf(s);              // |K·w| small: no max-shift needed
    if (lane == 0) { e_s[r] = e; eb[row] = f2bf(e); }
  }
  __syncthreads();

#pragma unroll
  for (int g = 0; g < 8; ++g) {
    const int jr = g * 4 + wid;
    const size_t row = (size_t)b * LK + j0 + jr;
    const float4 vv = reinterpret_cast<const float4*>(value + row * DD)[lane];
    const float e = e_s[jr];
    ushort4 u;
    u.x = f2bf(e * vv.x);
    u.y = f2bf(e * vv.y);
    u.z = f2bf(e * vv.z);
    u.w = f2bf(e * vv.w);
    *reinterpret_cast<ushort4*>(&t_s[jr][lane * 4]) = u;
  }
  __syncthreads();

  // frag gather: lane holds B[k=8*(lane>>4)+i][d=n*16+(lane&15)]
  const int lr = lane & 15;
  const int lj = lane >> 4;
#pragma unroll
  for (int n4 = 0; n4 < 4; ++n4) {
    const int n = wid * 4 + n4;
    ushort8v va;
#pragma unroll
    for (int i = 0; i < 8; ++i) va[i] = t_s[lj * 8 + i][n * 16 + lr];
    *reinterpret_cast<ushort8v*>(
        evB + ((size_t)((b * 64 + ks) * 16 + n) * 64 + lane) * 8) = va;
  }
}

// ---------------- Kernel 2: mask-streaming masked GEMM ------------------------
// grid 256 (1 block/CU): blk = b + 8*itile. 512 thr = 8 waves (2m x 4n).
// Block tile: 64 rows x 256 d; wave (wm,wn): rows [wm*32,+32), d [wn*64,+64).
__global__ __launch_bounds__(512, 1) void bah_gemm(
    const int* __restrict__ mask, const unsigned short* __restrict__ evB,
    const unsigned short* __restrict__ eb, float* __restrict__ out)
{
  __shared__ unsigned short A_s[3][64 * 64];   // 3-deep ring, 24 KB, XOR-swizzled
  __shared__ float denom_s[64];

  const int t = threadIdx.x;
  const int lane = t & 63;
  const int wid = t >> 6;                   // 0..7
  const int wm = wid >> 2;                  // 0..1: 32-row half
  const int wn = wid & 3;                   // 0..3: 64-d quarter
  const int lr = lane & 15;
  const int lj = lane >> 4;

  const int blk = blockIdx.x;
  const int b = blk & 7;                    // batch -> XCD (evB L2-resident)
  const int i0 = (blk >> 3) * 64;

  // ---- A staging: 8 thr/row; thread owns ints [q*8, q*8+8) = 32 B contiguous
  //      (2 int4 loads) -> one uint4 (8 bf16) -> LDS slot q ^ (sr&7). ----
  const int sr = t >> 3;                    // 0..63
  const int q = t & 7;
  const int* aptr = mask + ((size_t)b * LQ + i0 + sr) * LK + q * 8;
  const int awr = sr * 64 + ((q ^ (sr & 7)) * 8);   // ushort slot (16 B)

  // B frag pointers (pre-fragged evB): stride 8192 ushorts per 32-k slice
  const unsigned short* bB[4];
#pragma unroll
  for (int nn = 0; nn < 4; ++nn)
    bB[nn] = evB + ((size_t)(b * 64) * 16 + wn * 4 + nn) * 512 + lane * 8;
  const unsigned short* ebb = eb + b * LK + lj * 8;

  // A frag read offsets: row = wm*32 + m*16 + lr; chunk (h*4+lj) ^ (row&7)
  int afo[2][2];
#pragma unroll
  for (int m = 0; m < 2; ++m) {
    const int row = wm * 32 + m * 16 + lr;
#pragma unroll
    for (int h = 0; h < 2; ++h)
      afo[m][h] = row * 64 + (((h * 4 + lj) ^ (row & 7)) * 8);
  }

  f32x4 acc[2][4] = {};
  f32x4 accd[2] = {};
  const short8v z8 = {};

  short8v bfr[2][2][4];                     // [buf][h][nn] — 1 step ahead
  short8v efr[2][2] = {{z8, z8}, {z8, z8}};

  // ---- prologue: A(0)->ring0; A(1)->regs; B(0)/e(0)->reg buf0 ----
  {
    const int4 p0 = *reinterpret_cast<const int4*>(aptr);
    const int4 p1 = *reinterpret_cast<const int4*>(aptr + 4);
    *reinterpret_cast<uint4*>(&A_s[0][awr]) = pack_mask8(p0, p1);
  }
  int4 aC0 = *reinterpret_cast<const int4*>(aptr + 64);
  int4 aC1 = *reinterpret_cast<const int4*>(aptr + 68);
#pragma unroll
  for (int h = 0; h < 2; ++h) {
#pragma unroll
    for (int nn = 0; nn < 4; ++nn)
      bfr[0][h][nn] = *reinterpret_cast<const short8v*>(bB[nn] + (size_t)h * 8192);
    if (wn == 0 && lr == 0)
      efr[0][h] = *reinterpret_cast<const short8v*>(ebb + h * 32);
  }
  __syncthreads();

#pragma unroll 2
  for (int tt = 0; tt < 32; ++tt) {
    const int cur = tt & 1;
    const int nxt = cur ^ 1;
    const int bufC = tt % 3;
    const int bufW = (tt + 1) % 3;

    // ---- issue: A(t+2), B(t+1), e(t+1) (cross barrier via counted vmcnt) ----
    const int k2 = ((tt + 2) & 31) * 64;    // wrap: dead loads, harmless
    const int4 aN0 = *reinterpret_cast<const int4*>(aptr + k2);
    const int4 aN1 = *reinterpret_cast<const int4*>(aptr + k2 + 4);
    const int kn = ((tt + 1) & 31) * 2;
#pragma unroll
    for (int h = 0; h < 2; ++h) {
#pragma unroll
      for (int nn = 0; nn < 4; ++nn)
        bfr[nxt][h][nn] = *reinterpret_cast<const short8v*>(
            bB[nn] + (size_t)(kn + h) * 8192);
      short8v ev = z8;
      if (wn == 0 && lr == 0)
        ev = *reinterpret_cast<const short8v*>(ebb + (kn + h) * 32);
      efr[nxt][h] = ev;
    }
    __builtin_amdgcn_sched_barrier(0);

    // ---- write A(t+1) from regs; certify with lgkm + barrier only ----
    *reinterpret_cast<uint4*>(&A_s[bufW][awr]) = pack_mask8(aC0, aC1);
    asm volatile("s_waitcnt lgkmcnt(0)" ::: "memory");
    __builtin_amdgcn_sched_barrier(0);
    __builtin_amdgcn_s_barrier();
    __builtin_amdgcn_sched_barrier(0);

    // ---- compute tile t from LDS-A + reg-B ----
#pragma unroll
    for (int h = 0; h < 2; ++h) {
      short8v af[2];
#pragma unroll
      for (int m = 0; m < 2; ++m)
        af[m] = *reinterpret_cast<const short8v*>(&A_s[bufC][afo[m][h]]);
      __builtin_amdgcn_s_setprio(1);
      if (wn == 0) {
#pragma unroll
        for (int m = 0; m < 2; ++m)
          accd[m] = __builtin_amdgcn_mfma_f32_16x16x32_bf16(
              af[m], efr[cur][h], accd[m], 0, 0, 0);
      }
#pragma unroll
      for (int m = 0; m < 2; ++m)
#pragma unroll
        for (int nn = 0; nn < 4; ++nn)
          acc[m][nn] = __builtin_amdgcn_mfma_f32_16x16x32_bf16(
              af[m], bfr[cur][h][nn], acc[m][nn], 0, 0, 0);
      __builtin_amdgcn_s_setprio(0);
    }
    aC0 = aN0; aC1 = aN1;
  }

  // ---- denominator broadcast (C col 0 lives in lanes with lr==0) ----
  if (wn == 0 && lr == 0) {
#pragma unroll
    for (int m = 0; m < 2; ++m)
#pragma unroll
      for (int qq = 0; qq < 4; ++qq)
        denom_s[wm * 32 + m * 16 + lj * 4 + qq] = accd[m][qq];
  }
  __syncthreads();

  // ---- epilogue: divide and store (C layout: col=lane&15, row=lj*4+q) ----
#pragma unroll
  for (int m = 0; m < 2; ++m) {
    const int row0 = wm * 32 + m * 16 + lj * 4;
    float inv[4];
#pragma unroll
    for (int qq = 0; qq < 4; ++qq) {
      const float dn = denom_s[row0 + qq];
      inv[qq] = (dn != 0.f) ? 1.f / dn : 0.f;   // all-masked row: avoid NaN
    }
#pragma unroll
    for (int nn = 0; nn < 4; ++nn) {
      const int col = wn * 64 + nn * 16 + lr;
#pragma unroll
      for (int qq = 0; qq < 4; ++qq)
        out[((size_t)b * LQ + (i0 + row0 + qq)) * DD + col] = acc[m][nn][qq] * inv[qq];
    }
  }
}

extern "C" void kernel_launch(void* const* d_in, const int* in_sizes, int n_in,
                              void* d_out, int out_size, void* d_ws, size_t ws_size,
                              hipStream_t stream) {
  // inputs: 0=query (unused: softmax shift-invariance), 1=key, 2=value, 3=mask, 4=w_align
  const float* key   = (const float*)d_in[1];
  const float* value = (const float*)d_in[2];
  const int*   mask  = (const int*)d_in[3];
  const float* w     = (const float*)d_in[4];
  float* out = (float*)d_out;

  unsigned short* evB = (unsigned short*)d_ws;                              // 8 MB
  unsigned short* eb  = (unsigned short*)((char*)d_ws + (size_t)NB * DD * LK * 2);

  bah_precompute<<<NB * (LK / 32), 256, 0, stream>>>(key, value, w, evB, eb);
  bah_gemm<<<256, 512, 0, stream>>>(mask, evB, eb, out);
}